// Round 15
// baseline (211.978 us; speedup 1.0000x reference)
//
#include <hip/hip_runtime.h>
#include <math.h>

#define N_   128
#define H_   400
#define W_   400
#define MS_  28
#define CT_  80
#define CS_  53
#define HW_  (H_*W_)
#define NCH_ (CS_ + N_)   // 181
#define WG_  1600
#define IGN_ 255
#define G_   8            // channel groups == waves per block
#define NTH_G 16          // thing channels per group: 128/8 exactly
#define PPT_ 2            // pixels per thread (float2)
#define BT_  512          // 8 waves per block; wave w = channel group w
#define TPX_ 128          // pixels per block (64 lanes * PPT)
#define GX_  (HW_/TPX_)   // 1250 blocks (exact)
#define NSMAX_ 7          // max stuff channels per group

typedef float f2 __attribute__((ext_vector_type(2)));

#define NT_LD(p)    __builtin_nontemporal_load(p)
#define NT_ST(v, p) __builtin_nontemporal_store((v), (p))

struct NParam {
  int vy_lo, vy_hi, vx_lo, vx_hi;   // mask-valid box (inclusive)
  int cy1, cy2, cx1, cx2;           // sem box (y in [cy1,cy2), x in [cx1,cx2))
  float sy, sx;                     // 28/hh, 28/ww
  int y0b, x0b;                     // floor(bbox/4)
  int mlbase, thbase;               // offsets into mask_logits / thing_logit
  int pad0, pad1;                   // 64 B
};

// Device globals. g_done is an EPOCH counter (monotonic, old%GX picks the
// winner) -> no zeroing needed, graph-replay and rocprof-replay safe.
// g_part is fully rewritten each launch before being read; cross-block
// traffic uses agent-scope (cache-bypassing) accesses -> no reliance on
// cross-XCD L2 coherence.
__device__ unsigned int g_done;           // global ticket
__device__ float        g_part[GX_*2];    // per-block (nll,cnt) partials

#define AG_ST(p, v) __hip_atomic_store((p), (v), __ATOMIC_RELAXED, __HIP_MEMORY_SCOPE_AGENT)
#define AG_LD(p)    __hip_atomic_load((p), __ATOMIC_RELAXED, __HIP_MEMORY_SCOPE_AGENT)

__device__ __forceinline__ void lse_update(float v, float& m, float& s) {
  float d = v - m;
  float e = __expf(-fabsf(d));
  s = (d > 0.0f) ? fmaf(s, e, 1.0f) : (s + e);
  m = fmaxf(m, v);
}

// Fused, single-block-per-tile: 8 waves = 8 channel groups (c % 8 == w),
// all covering the SAME 128 pixels; intra-block LDS combine.
// Issue-early / consume-late discipline (all LOADS precede all STORES in
// issue order -> with in-order vmcnt retirement, every consume waits only
// on its load, never on store drain):
//   issue gt(2) -> issue stuff(6-7) -> preload <=2 active thing values ->
//   zero-store burst(~15) -> clamp tcs -> consume stuff -> actives.
__global__ __launch_bounds__(512) void main_kernel(
    const float* __restrict__ mask_logits,
    const float* __restrict__ stuff_logit,
    const float* __restrict__ thing_logit,
    const float* __restrict__ bbox,
    const int*   __restrict__ cls_idx,
    const int*   __restrict__ gt,
    float* __restrict__ out)
{
  __shared__ NParam spar[N_];
  __shared__ int4   sbox[N_];       // superbox = union(sem, mask), inclusive
  __shared__ float  lp_lds[G_][TPX_];
  __shared__ float  vt_lds[TPX_];
  __shared__ float  red[16];
  __shared__ unsigned s_fin;
  int tid = threadIdx.x;
  if (tid < N_) {
    int n = tid;
    float b0 = bbox[4*n+0]*0.25f, b1 = bbox[4*n+1]*0.25f,
          b2 = bbox[4*n+2]*0.25f, b3 = bbox[4*n+3]*0.25f;
    int x0b = (int)floorf(b0), y0b = (int)floorf(b1);
    int x2b = (int)floorf(b2), y2b = (int)floorf(b3);
    int hh = y2b - y0b + 1, ww = x2b - x0b + 1;
    NParam p;
    p.vy_lo = max(y0b, 0); p.vy_hi = min(y2b, H_-1);
    p.vx_lo = max(x0b, 0); p.vx_hi = min(x2b, W_-1);
    p.cy1 = (int)b1; p.cx1 = (int)b0;                 // trunc (positive)
    p.cy2 = (int)(rintf(b3) + 1.0f);                  // jnp.round = RNE
    p.cx2 = (int)(rintf(b2) + 1.0f);
    p.sy = 28.0f / (float)hh; p.sx = 28.0f / (float)ww;
    p.y0b = y0b; p.x0b = x0b;
    int cls = cls_idx[n];
    p.mlbase = (n*CT_ + cls)*(MS_*MS_);
    p.thbase = cls*HW_;
    p.pad0 = 0; p.pad1 = 0;
    spar[n] = p;
    sbox[n] = make_int4(min(p.vy_lo, p.cy1), max(p.vy_hi, p.cy2 - 1),
                        min(p.vx_lo, p.cx1), max(p.vx_hi, p.cx2 - 1));
  }
  __syncthreads();

  int grp  = tid >> 6;              // wave id == channel group
  int lane = tid & 63;
  int pix0 = blockIdx.x*TPX_ + lane*PPT_;
  int y  = pix0 / W_;               // W_ even, pix0 even -> pair shares row
  int xb = pix0 - y*W_;
  // first thing channel of this group: smallest c>=53 with c%8==grp
  int cth_start = CS_ + ((grp - (CS_ & 7)) & 7);
  // stuff channels of this group: grp, grp+8, ... < 53
  int ns = (grp <= 4) ? 7 : 6;      // wave-uniform trip count

  // ---- issue gt loads (consumed LAST -- clamp deferred past the burst) ----
  int graw[PPT_];
  #pragma unroll
  for (int k = 0; k < PPT_; ++k)
    graw[k] = gt[y*(4*WG_) + (xb + k)*4];

  // ---- issue ALL stuff loads (stay in flight through the burst) ----
  f2 vls[NSMAX_];
  #pragma unroll
  for (int i = 0; i < NSMAX_; ++i) {
    if (i < ns)
      vls[i] = NT_LD((const f2*)(stuff_logit + (grp + 8*i)*HW_ + pix0));
  }

  // ---- thing bitmask (LDS only, no vmem consume) ----
  unsigned amask = 0u;
  #pragma unroll
  for (int i = 0; i < NTH_G; ++i) {
    int4 u = sbox[cth_start - CS_ + 8*i];
    bool rej = (y < u.x) | (y > u.y) | (xb > u.w) | (xb + PPT_ - 1 < u.z);
    if (!__all(rej)) amask |= (1u << i);
  }
  amask = __builtin_amdgcn_readfirstlane(amask);  // SGPR -> scalar branches
  int zc = NTH_G - __popc(amask);   // wave-uniform

  // ---- preload thing_logit for the first <=2 active channels ----
  // (active set is wave-uniform -> static slots; unconditional load is
  // in-bounds; per-pixel box predicate applied at consume time)
  int ia0 = -1, ia1 = -1;
  { unsigned t = amask;
    if (t) { ia0 = __builtin_ctz((int)t); t &= t - 1u; }
    if (t) { ia1 = __builtin_ctz((int)t); } }
  f2 tv0 = {0.0f, 0.0f}, tv1 = {0.0f, 0.0f};
  if (ia0 >= 0)
    tv0 = NT_LD((const f2*)(thing_logit + spar[cth_start - CS_ + 8*ia0].thbase + pix0));
  if (ia1 >= 0)
    tv1 = NT_LD((const f2*)(thing_logit + spar[cth_start - CS_ + 8*ia1].thbase + pix0));

  // ---- zero-store burst (pure stores; covers ALL the above loads) ----
  {
    f2 z = {0.0f, 0.0f};
    for (int i = 0; i < NTH_G; ++i) {
      if (!((amask >> i) & 1u))
        NT_ST(z, (f2*)(out + (cth_start + 8*i)*HW_ + pix0));
    }
  }

  // ---- clamp tcs (gt wait covered by the burst) ----
  int tcs[PPT_];
  #pragma unroll
  for (int k = 0; k < PPT_; ++k)
    tcs[k] = min(max(graw[k], 0), NCH_-1);

  float mv[PPT_], sv[PPT_], vts[PPT_];
  #pragma unroll
  for (int k = 0; k < PPT_; ++k) { mv[k] = -INFINITY; sv[k] = 0.0f; vts[k] = 0.0f; }

  // ---- consume stuff values (loads long since landed) ----
  #pragma unroll
  for (int i = 0; i < NSMAX_; ++i) {
    if (i < ns) {
      int c = grp + 8*i;
      NT_ST(vls[i], (f2*)(out + c*HW_ + pix0));
      #pragma unroll
      for (int k = 0; k < PPT_; ++k) {
        lse_update(vls[i][k], mv[k], sv[k]);
        if (c == tcs[k]) vts[k] = vls[i][k];
      }
    }
  }

  // ---- active thing channels (expected ~1-2 per wave) ----
  unsigned am = amask;
  while (am) {
    int i = __builtin_ctz(am); am &= am - 1u;
    int cc = cth_start + 8*i;
    NParam p = spar[cc - CS_];
    float vv[PPT_] = {0.0f, 0.0f};
    {
      f2 t;
      if (i == ia0)      t = tv0;                     // preloaded (scalar branch)
      else if (i == ia1) t = tv1;
      else t = NT_LD((const f2*)(thing_logit + p.thbase + pix0));
      #pragma unroll
      for (int k = 0; k < PPT_; ++k) {
        int x = xb + k;
        if (y >= p.cy1 && y < p.cy2 && x >= p.cx1 && x < p.cx2) vv[k] = t[k];
      }
    }
    if (y >= p.vy_lo && y <= p.vy_hi && xb <= p.vx_hi && xb+PPT_-1 >= p.vx_lo) {
      float srcy = ((float)(y - p.y0b) + 0.5f)*p.sy - 0.5f;
      float fy = floorf(srcy); float ty = srcy - fy;
      int i0 = (int)fminf(fmaxf(fy,        0.0f), (float)(MS_-1));
      int i1 = (int)fminf(fmaxf(fy + 1.0f, 0.0f), (float)(MS_-1));
      const float* r0p = mask_logits + p.mlbase + i0*MS_;
      const float* r1p = mask_logits + p.mlbase + i1*MS_;
      #pragma unroll
      for (int k = 0; k < PPT_; ++k) {
        int x = xb + k;
        if (x >= p.vx_lo && x <= p.vx_hi) {
          float srcx = ((float)(x - p.x0b) + 0.5f)*p.sx - 0.5f;
          float fx = floorf(srcx); float tx = srcx - fx;
          int j0 = (int)fminf(fmaxf(fx,        0.0f), (float)(MS_-1));
          int j1 = (int)fminf(fmaxf(fx + 1.0f, 0.0f), (float)(MS_-1));
          float r0 = r0p[j0]*(1.0f - tx) + r0p[j1]*tx;
          float r1 = r1p[j0]*(1.0f - tx) + r1p[j1]*tx;
          vv[k] += r0*(1.0f - ty) + r1*ty;
        }
      }
    }
    f2 ov = {vv[0], vv[1]};
    NT_ST(ov, (f2*)(out + cc*HW_ + pix0));
    #pragma unroll
    for (int k = 0; k < PPT_; ++k) {
      lse_update(vv[k], mv[k], sv[k]);
      if (cc == tcs[k]) vts[k] = vv[k];
    }
  }

  // merge skipped zero-channels analytically; lp -> LDS
  {
    float zcf = (float)zc;
    #pragma unroll
    for (int k = 0; k < PPT_; ++k) {
      float m = mv[k], s = sv[k];
      if (zc > 0) {
        if (m >= 0.0f) { s = fmaf(zcf, __expf(-m), s); }
        else           { s = fmaf(s, __expf(m), zcf); m = 0.0f; }  // m=-inf ok: s->zcf
      }
      lp_lds[grp][lane*PPT_ + k] = m + __logf(s);
      // exactly one wave owns each pixel's target channel (tcs % 8 == grp)
      if ((tcs[k] & (G_-1)) == grp) vt_lds[lane*PPT_ + k] = vts[k];
    }
  }
  __syncthreads();

  // ---- intra-block combine: threads 0..127, one pixel each ----
  float nll = 0.0f, cnt = 0.0f;
  if (tid < TPX_) {
    int p = blockIdx.x*TPX_ + tid;
    float m = lp_lds[0][tid], s = 1.0f;
    #pragma unroll
    for (int g = 1; g < G_; ++g) {
      float lg = lp_lds[g][tid];
      float d = lg - m;
      float e = __expf(-fabsf(d));
      s = (d > 0.0f) ? fmaf(s, e, 1.0f) : (s + e);
      m = fmaxf(m, lg);
    }
    int yy = p / W_;
    int xx = p - yy*W_;
    int gv = gt[yy*(4*WG_) + xx*4];   // L1/L2-hot (loaded above)
    bool valid = (gv != IGN_);
    nll = valid ? (m + __logf(s) - vt_lds[tid]) : 0.0f;
    cnt = valid ? 1.0f : 0.0f;
  }

  // block reduce (threads >=128 contribute 0)
  for (int off = 32; off >= 1; off >>= 1) {
    nll += __shfl_down(nll, off, 64);
    cnt += __shfl_down(cnt, off, 64);
  }
  int wid = tid >> 6;
  if ((tid & 63) == 0) { red[wid*2] = nll; red[wid*2+1] = cnt; }
  __syncthreads();
  if (tid == 0) {
    float ts = red[0] + red[2], tcn = red[1] + red[3];   // only waves 0-1 nonzero
    AG_ST(&g_part[blockIdx.x*2],     ts);
    AG_ST(&g_part[blockIdx.x*2 + 1], tcn);
    // same-thread order: partial stores must COMPLETE before the ticket
    asm volatile("s_waitcnt vmcnt(0)" ::: "memory");
    unsigned d = __hip_atomic_fetch_add(&g_done, 1u,
                                        __ATOMIC_RELAXED, __HIP_MEMORY_SCOPE_AGENT);
    s_fin = ((d % (unsigned)GX_) == (unsigned)(GX_-1)) ? 1u : 0u;
  }
  __syncthreads();
  if (s_fin) {
    // last block overall: fold GX_=1250 partials, write the loss
    float a = 0.0f, b = 0.0f;
    for (int i = tid; i < GX_; i += BT_) {
      a += AG_LD(&g_part[i*2]);
      b += AG_LD(&g_part[i*2 + 1]);
    }
    for (int off = 32; off >= 1; off >>= 1) {
      a += __shfl_down(a, off, 64);
      b += __shfl_down(b, off, 64);
    }
    if ((tid & 63) == 0) { red[wid*2] = a; red[wid*2+1] = b; }
    __syncthreads();
    if (tid == 0) {
      float ts = 0.0f, tcn = 0.0f;
      #pragma unroll
      for (int i = 0; i < 8; ++i) { ts += red[i*2]; tcn += red[i*2+1]; }
      out[NCH_*HW_] = ts / fmaxf(tcn, 1.0f);   // LOSS_W = 1.0
    }
  }
}

extern "C" void kernel_launch(void* const* d_in, const int* in_sizes, int n_in,
                              void* d_out, int out_size, void* d_ws, size_t ws_size,
                              hipStream_t stream) {
  const float* mask_logits = (const float*)d_in[0];
  const float* stuff_logit = (const float*)d_in[1];
  const float* thing_logit = (const float*)d_in[2];
  const float* bbox        = (const float*)d_in[3];
  const int*   cls_idx     = (const int*)d_in[4];
  const int*   gt          = (const int*)d_in[5];
  float* out = (float*)d_out;

  main_kernel<<<GX_, BT_, 0, stream>>>(mask_logits, stuff_logit, thing_logit,
                                       bbox, cls_idx, gt, out);
}

// Round 16
// 211.512 us; speedup vs baseline: 1.0022x; 1.0022x over previous
//
#include <hip/hip_runtime.h>
#include <math.h>

#define N_   128
#define H_   400
#define W_   400
#define MS_  28
#define CT_  80
#define CS_  53
#define HW_  (H_*W_)
#define NCH_ (CS_ + N_)   // 181
#define WG_  1600
#define IGN_ 255
#define G_   8            // channel groups == waves per block
#define NTH_G 16          // thing channels per group: 128/8 exactly
#define PPT_ 4            // pixels per thread (float4, 16 B/lane)
#define BT_  512          // 8 waves per block; wave w = channel group w
#define TPX_ 256          // pixels per block (64 lanes * PPT)
#define GX_  (HW_/TPX_)   // 625 blocks (exact)
#define NSMAX_ 7          // max stuff channels per group

typedef float f4 __attribute__((ext_vector_type(4)));

#define NT_LD(p)    __builtin_nontemporal_load(p)
#define NT_ST(v, p) __builtin_nontemporal_store((v), (p))

struct NParam {
  int vy_lo, vy_hi, vx_lo, vx_hi;   // mask-valid box (inclusive)
  int cy1, cy2, cx1, cx2;           // sem box (y in [cy1,cy2), x in [cx1,cx2))
  float sy, sx;                     // 28/hh, 28/ww
  int y0b, x0b;                     // floor(bbox/4)
  int mlbase, thbase;               // offsets into mask_logits / thing_logit
  int pad0, pad1;                   // 64 B
};

// Device globals. g_done is an EPOCH counter (monotonic, old%GX picks the
// winner) -> no zeroing needed, graph-replay and rocprof-replay safe.
// g_part is fully rewritten each launch before being read; cross-block
// traffic uses agent-scope (cache-bypassing) accesses -> no reliance on
// cross-XCD L2 coherence.
__device__ unsigned int g_done;           // global ticket
__device__ float        g_part[GX_*2];    // per-block (nll,cnt) partials

#define AG_ST(p, v) __hip_atomic_store((p), (v), __ATOMIC_RELAXED, __HIP_MEMORY_SCOPE_AGENT)
#define AG_LD(p)    __hip_atomic_load((p), __ATOMIC_RELAXED, __HIP_MEMORY_SCOPE_AGENT)

__device__ __forceinline__ void lse_update(float v, float& m, float& s) {
  float d = v - m;
  float e = __expf(-fabsf(d));
  s = (d > 0.0f) ? fmaf(s, e, 1.0f) : (s + e);
  m = fmaxf(m, v);
}

// Fused, single-block-per-tile: 8 waves = 8 channel groups (c % 8 == w),
// all covering the SAME 256 pixels; intra-block LDS combine.
// r14 structure (batch-issue stuff loads -> zero-store burst covers their
// latency -> consume), widened to 16 B/lane transactions (PPT=4): halves
// instruction count, doubles per-access bytes; per-CU in-flight bytes
// unchanged (19.5 waves x 7 KB vs 39 x 3.5 KB).
__global__ __launch_bounds__(512) void main_kernel(
    const float* __restrict__ mask_logits,
    const float* __restrict__ stuff_logit,
    const float* __restrict__ thing_logit,
    const float* __restrict__ bbox,
    const int*   __restrict__ cls_idx,
    const int*   __restrict__ gt,
    float* __restrict__ out)
{
  __shared__ NParam spar[N_];
  __shared__ int4   sbox[N_];       // superbox = union(sem, mask), inclusive
  __shared__ float  lp_lds[G_][TPX_];
  __shared__ float  vt_lds[TPX_];
  __shared__ float  red[16];
  __shared__ unsigned s_fin;
  int tid = threadIdx.x;
  if (tid < N_) {
    int n = tid;
    float b0 = bbox[4*n+0]*0.25f, b1 = bbox[4*n+1]*0.25f,
          b2 = bbox[4*n+2]*0.25f, b3 = bbox[4*n+3]*0.25f;
    int x0b = (int)floorf(b0), y0b = (int)floorf(b1);
    int x2b = (int)floorf(b2), y2b = (int)floorf(b3);
    int hh = y2b - y0b + 1, ww = x2b - x0b + 1;
    NParam p;
    p.vy_lo = max(y0b, 0); p.vy_hi = min(y2b, H_-1);
    p.vx_lo = max(x0b, 0); p.vx_hi = min(x2b, W_-1);
    p.cy1 = (int)b1; p.cx1 = (int)b0;                 // trunc (positive)
    p.cy2 = (int)(rintf(b3) + 1.0f);                  // jnp.round = RNE
    p.cx2 = (int)(rintf(b2) + 1.0f);
    p.sy = 28.0f / (float)hh; p.sx = 28.0f / (float)ww;
    p.y0b = y0b; p.x0b = x0b;
    int cls = cls_idx[n];
    p.mlbase = (n*CT_ + cls)*(MS_*MS_);
    p.thbase = cls*HW_;
    p.pad0 = 0; p.pad1 = 0;
    spar[n] = p;
    sbox[n] = make_int4(min(p.vy_lo, p.cy1), max(p.vy_hi, p.cy2 - 1),
                        min(p.vx_lo, p.cx1), max(p.vx_hi, p.cx2 - 1));
  }
  __syncthreads();

  int grp  = tid >> 6;              // wave id == channel group
  int lane = tid & 63;
  int pix0 = blockIdx.x*TPX_ + lane*PPT_;
  int y  = pix0 / W_;               // W_ % 4 == 0 -> all 4 px share row
  int xb = pix0 - y*W_;
  // first thing channel of this group: smallest c>=53 with c%8==grp
  int cth_start = CS_ + ((grp - (CS_ & 7)) & 7);
  // stuff channels of this group: grp, grp+8, ... < 53
  int ns = (grp <= 4) ? 7 : 6;      // wave-uniform trip count

  // target channel per pixel (gt line reused in combine -> cached)
  int tcs[PPT_];
  #pragma unroll
  for (int k = 0; k < PPT_; ++k) {
    int g = gt[y*(4*WG_) + (xb + k)*4];
    tcs[k] = min(max(g, 0), NCH_-1);
  }

  // ---- issue ALL stuff loads up front (stay in flight through the burst) --
  f4 vls[NSMAX_];
  #pragma unroll
  for (int i = 0; i < NSMAX_; ++i) {
    if (i < ns)
      vls[i] = NT_LD((const f4*)(stuff_logit + (grp + 8*i)*HW_ + pix0));
  }

  float mv[PPT_], sv[PPT_], vts[PPT_];
  #pragma unroll
  for (int k = 0; k < PPT_; ++k) { mv[k] = -INFINITY; sv[k] = 0.0f; vts[k] = 0.0f; }

  // ---- thing bitmask (LDS only) + zero-store burst (covers load latency) --
  unsigned amask = 0u;
  #pragma unroll
  for (int i = 0; i < NTH_G; ++i) {
    int4 u = sbox[cth_start - CS_ + 8*i];
    bool rej = (y < u.x) | (y > u.y) | (xb > u.w) | (xb + PPT_ - 1 < u.z);
    if (!__all(rej)) amask |= (1u << i);
  }
  amask = __builtin_amdgcn_readfirstlane(amask);  // SGPR -> scalar branches
  int zc = NTH_G - __popc(amask);   // wave-uniform
  {
    f4 z = {0.0f, 0.0f, 0.0f, 0.0f};
    for (int i = 0; i < NTH_G; ++i) {
      if (!((amask >> i) & 1u))
        NT_ST(z, (f4*)(out + (cth_start + 8*i)*HW_ + pix0));
    }
  }

  // ---- consume stuff values (loads have had the whole burst to land) ----
  #pragma unroll
  for (int i = 0; i < NSMAX_; ++i) {
    if (i < ns) {
      int c = grp + 8*i;
      NT_ST(vls[i], (f4*)(out + c*HW_ + pix0));
      #pragma unroll
      for (int k = 0; k < PPT_; ++k) {
        lse_update(vls[i][k], mv[k], sv[k]);
        if (c == tcs[k]) vts[k] = vls[i][k];
      }
    }
  }

  // ---- active thing channels (expected ~1-2 per wave) ----
  unsigned am = amask;
  while (am) {
    int i = __builtin_ctz(am); am &= am - 1u;
    int cc = cth_start + 8*i;
    NParam p = spar[cc - CS_];
    float vv[PPT_] = {0.0f, 0.0f, 0.0f, 0.0f};
    if (y >= p.cy1 && y < p.cy2 && xb < p.cx2 && xb+PPT_-1 >= p.cx1) {
      f4 t = NT_LD((const f4*)(thing_logit + p.thbase + pix0));
      #pragma unroll
      for (int k = 0; k < PPT_; ++k) {
        int x = xb + k;
        if (x >= p.cx1 && x < p.cx2) vv[k] = t[k];
      }
    }
    if (y >= p.vy_lo && y <= p.vy_hi && xb <= p.vx_hi && xb+PPT_-1 >= p.vx_lo) {
      float srcy = ((float)(y - p.y0b) + 0.5f)*p.sy - 0.5f;
      float fy = floorf(srcy); float ty = srcy - fy;
      int i0 = (int)fminf(fmaxf(fy,        0.0f), (float)(MS_-1));
      int i1 = (int)fminf(fmaxf(fy + 1.0f, 0.0f), (float)(MS_-1));
      const float* r0p = mask_logits + p.mlbase + i0*MS_;
      const float* r1p = mask_logits + p.mlbase + i1*MS_;
      #pragma unroll
      for (int k = 0; k < PPT_; ++k) {
        int x = xb + k;
        if (x >= p.vx_lo && x <= p.vx_hi) {
          float srcx = ((float)(x - p.x0b) + 0.5f)*p.sx - 0.5f;
          float fx = floorf(srcx); float tx = srcx - fx;
          int j0 = (int)fminf(fmaxf(fx,        0.0f), (float)(MS_-1));
          int j1 = (int)fminf(fmaxf(fx + 1.0f, 0.0f), (float)(MS_-1));
          float r0 = r0p[j0]*(1.0f - tx) + r0p[j1]*tx;
          float r1 = r1p[j0]*(1.0f - tx) + r1p[j1]*tx;
          vv[k] += r0*(1.0f - ty) + r1*ty;
        }
      }
    }
    f4 ov = {vv[0], vv[1], vv[2], vv[3]};
    NT_ST(ov, (f4*)(out + cc*HW_ + pix0));
    #pragma unroll
    for (int k = 0; k < PPT_; ++k) {
      lse_update(vv[k], mv[k], sv[k]);
      if (cc == tcs[k]) vts[k] = vv[k];
    }
  }

  // merge skipped zero-channels analytically; lp -> LDS
  {
    float zcf = (float)zc;
    #pragma unroll
    for (int k = 0; k < PPT_; ++k) {
      float m = mv[k], s = sv[k];
      if (zc > 0) {
        if (m >= 0.0f) { s = fmaf(zcf, __expf(-m), s); }
        else           { s = fmaf(s, __expf(m), zcf); m = 0.0f; }  // m=-inf ok: s->zcf
      }
      lp_lds[grp][lane*PPT_ + k] = m + __logf(s);
      // exactly one wave owns each pixel's target channel (tcs % 8 == grp)
      if ((tcs[k] & (G_-1)) == grp) vt_lds[lane*PPT_ + k] = vts[k];
    }
  }
  __syncthreads();

  // ---- intra-block combine: threads 0..255, one pixel each ----
  float nll = 0.0f, cnt = 0.0f;
  if (tid < TPX_) {
    int p = blockIdx.x*TPX_ + tid;
    float m = lp_lds[0][tid], s = 1.0f;
    #pragma unroll
    for (int g = 1; g < G_; ++g) {
      float lg = lp_lds[g][tid];
      float d = lg - m;
      float e = __expf(-fabsf(d));
      s = (d > 0.0f) ? fmaf(s, e, 1.0f) : (s + e);
      m = fmaxf(m, lg);
    }
    int yy = p / W_;
    int xx = p - yy*W_;
    int gv = gt[yy*(4*WG_) + xx*4];   // L1/L2-hot (loaded above)
    bool valid = (gv != IGN_);
    nll = valid ? (m + __logf(s) - vt_lds[tid]) : 0.0f;
    cnt = valid ? 1.0f : 0.0f;
  }

  // block reduce (threads >= TPX_ contribute 0)
  for (int off = 32; off >= 1; off >>= 1) {
    nll += __shfl_down(nll, off, 64);
    cnt += __shfl_down(cnt, off, 64);
  }
  int wid = tid >> 6;
  if ((tid & 63) == 0) { red[wid*2] = nll; red[wid*2+1] = cnt; }
  __syncthreads();
  if (tid == 0) {
    float ts = 0.0f, tcn = 0.0f;
    #pragma unroll
    for (int i = 0; i < 8; ++i) { ts += red[i*2]; tcn += red[i*2+1]; }
    AG_ST(&g_part[blockIdx.x*2],     ts);
    AG_ST(&g_part[blockIdx.x*2 + 1], tcn);
    // same-thread order: partial stores must COMPLETE before the ticket
    asm volatile("s_waitcnt vmcnt(0)" ::: "memory");
    unsigned d = __hip_atomic_fetch_add(&g_done, 1u,
                                        __ATOMIC_RELAXED, __HIP_MEMORY_SCOPE_AGENT);
    s_fin = ((d % (unsigned)GX_) == (unsigned)(GX_-1)) ? 1u : 0u;
  }
  __syncthreads();
  if (s_fin) {
    // last block overall: fold GX_=625 partials, write the loss
    float a = 0.0f, b = 0.0f;
    for (int i = tid; i < GX_; i += BT_) {
      a += AG_LD(&g_part[i*2]);
      b += AG_LD(&g_part[i*2 + 1]);
    }
    for (int off = 32; off >= 1; off >>= 1) {
      a += __shfl_down(a, off, 64);
      b += __shfl_down(b, off, 64);
    }
    if ((tid & 63) == 0) { red[wid*2] = a; red[wid*2+1] = b; }
    __syncthreads();
    if (tid == 0) {
      float ts = 0.0f, tcn = 0.0f;
      #pragma unroll
      for (int i = 0; i < 8; ++i) { ts += red[i*2]; tcn += red[i*2+1]; }
      out[NCH_*HW_] = ts / fmaxf(tcn, 1.0f);   // LOSS_W = 1.0
    }
  }
}

extern "C" void kernel_launch(void* const* d_in, const int* in_sizes, int n_in,
                              void* d_out, int out_size, void* d_ws, size_t ws_size,
                              hipStream_t stream) {
  const float* mask_logits = (const float*)d_in[0];
  const float* stuff_logit = (const float*)d_in[1];
  const float* thing_logit = (const float*)d_in[2];
  const float* bbox        = (const float*)d_in[3];
  const int*   cls_idx     = (const int*)d_in[4];
  const int*   gt          = (const int*)d_in[5];
  float* out = (float*)d_out;

  main_kernel<<<GX_, BT_, 0, stream>>>(mask_logits, stuff_logit, thing_logit,
                                       bbox, cls_idx, gt, out);
}